// Round 5
// baseline (595.516 us; speedup 1.0000x reference)
//
#include <hip/hip_runtime.h>

// Problem constants (B,S,D,H fixed by the reference)
#define Bsz 4
#define Ssz 2048
#define Dsz 1024
#define Hsz 4
#define HDsz 256
#define Msz 8192  // Bsz*Ssz

typedef unsigned short u16;
typedef __attribute__((ext_vector_type(8))) short bf16x8;  // 8 bf16 in 4 VGPRs
typedef __attribute__((ext_vector_type(4))) float f32x4;

__device__ __forceinline__ u16 f2b(float f) {  // fp32 -> bf16 RNE
  unsigned u = __float_as_uint(f);
  return (u16)((u + 0x7FFFu + ((u >> 16) & 1u)) >> 16);
}
__device__ __forceinline__ unsigned pk2(float a, float b) {
  return (unsigned)f2b(a) | ((unsigned)f2b(b) << 16);
}
__device__ __forceinline__ float b2f(unsigned lo16) {
  return __uint_as_float(lo16 << 16);
}

// async global->LDS, 16B per lane; LDS dest = wave-uniform base + lane*16
typedef const unsigned int __attribute__((address_space(1)))* gcp;
typedef unsigned int __attribute__((address_space(3)))* lcp;
__device__ __forceinline__ void gld16(const u16* g, u16* l) {
  __builtin_amdgcn_global_load_lds((gcp)g, (lcp)l, 16, 0, 0);
}

// ---------------------------------------------------------------------------
// fp32 -> bf16 elementwise
// ---------------------------------------------------------------------------
__global__ __launch_bounds__(256) void cvt_bf16(const float4* __restrict__ in,
                                                u16* __restrict__ outp) {
  size_t i = (size_t)blockIdx.x * 256 + threadIdx.x;
  float4 v = in[i];
  uint2 r; r.x = pk2(v.x, v.y); r.y = pk2(v.z, v.w);
  *(uint2*)(outp + i * 4) = r;
}

// ---------------------------------------------------------------------------
// bf16 MFMA GEMM (m97 structure): C[M,N] = A[M,K]*W[N,K]^T (+bias).
// 128x128 tile, BK=32, global_load_lds width-16 staging, unpadded [128][32]
// LDS. 4 waves x (4x4 of 16x16x32 MFMA). M=8192, N=K=1024.
// ---------------------------------------------------------------------------
__global__ __launch_bounds__(256) void gemm_lds(const u16* __restrict__ A16,
                                                const u16* __restrict__ Wb,
                                                const float* __restrict__ bias,
                                                float* __restrict__ C32,
                                                u16* __restrict__ Cbf) {
  __shared__ u16 sA[128 * 32];
  __shared__ u16 sB[128 * 32];
  const int tid = threadIdx.x;
  const int lane = tid & 63, quad = lane >> 4, l15 = lane & 15;
  const int w = tid >> 6;
  const int mw = (w >> 1) * 64, nw = (w & 1) * 64;
  const int m0 = blockIdx.y * 128, n0 = blockIdx.x * 128;
  const int r0 = tid >> 2, seg = (tid & 3) * 8;  // 4 lanes x 16B per row
  const u16* ga0 = A16 + (size_t)(m0 + r0) * Dsz + seg;
  const u16* gb0 = Wb + (size_t)(n0 + r0) * Dsz + seg;
  u16* lA0 = sA + w * 512;          // wave-uniform bases (u16 units)
  u16* lA1 = sA + 2048 + w * 512;
  u16* lB0 = sB + w * 512;
  u16* lB1 = sB + 2048 + w * 512;
  f32x4 acc[4][4] = {};
  for (int k0 = 0; k0 < Dsz; k0 += 32) {
    __syncthreads();
    gld16(ga0 + k0, lA0);
    gld16(ga0 + (size_t)64 * Dsz + k0, lA1);
    gld16(gb0 + k0, lB0);
    gld16(gb0 + (size_t)64 * Dsz + k0, lB1);
    __syncthreads();  // compiler drains vmcnt before barrier
    bf16x8 af[4], bfr[4];
#pragma unroll
    for (int i = 0; i < 4; ++i) {
      af[i] = *(const bf16x8*)&sA[(mw + i * 16 + l15) * 32 + quad * 8];
      bfr[i] = *(const bf16x8*)&sB[(nw + i * 16 + l15) * 32 + quad * 8];
    }
#pragma unroll
    for (int i = 0; i < 4; ++i)
#pragma unroll
      for (int j = 0; j < 4; ++j)
        acc[i][j] = __builtin_amdgcn_mfma_f32_16x16x32_bf16(af[i], bfr[j], acc[i][j], 0, 0, 0);
  }
#pragma unroll
  for (int j = 0; j < 4; ++j) {
    const int n = n0 + nw + j * 16 + l15;
    const float bv = bias ? bias[n] : 0.f;
#pragma unroll
    for (int i = 0; i < 4; ++i) {
#pragma unroll
      for (int r = 0; r < 4; ++r) {
        const int m = m0 + mw + i * 16 + quad * 4 + r;
        const float val = acc[i][j][r] + bv;
        const size_t idx = (size_t)m * Dsz + n;
        if (C32) C32[idx] = val;
        if (Cbf) Cbf[idx] = f2b(val);
      }
    }
  }
}

// ---------------------------------------------------------------------------
// V bf16 [b][s][h*256+e] -> V^T bf16 [bh][e][s]
// ---------------------------------------------------------------------------
__global__ __launch_bounds__(256) void transpose_v(const u16* __restrict__ V,
                                                   u16* __restrict__ Vt) {
  __shared__ u16 tile[32 * 36];
  const int t = threadIdx.x;
  const int s0 = blockIdx.x * 32, e0 = blockIdx.y * 32, bh = blockIdx.z;
  const int b = bh >> 2, h = bh & 3;
  {
    const int s_l = t >> 3, e8 = (t & 7) * 4;
    uint2 r = *(const uint2*)(V + ((size_t)(b * Ssz) + s0 + s_l) * Dsz + h * HDsz + e0 + e8);
    *(uint2*)&tile[s_l * 36 + e8] = r;
  }
  __syncthreads();
  {
    const int e_l = t >> 3, s4 = (t & 7) * 4;
    u16 a = tile[(s4 + 0) * 36 + e_l], b2 = tile[(s4 + 1) * 36 + e_l];
    u16 c = tile[(s4 + 2) * 36 + e_l], d = tile[(s4 + 3) * 36 + e_l];
    uint2 r; r.x = (unsigned)a | ((unsigned)b2 << 16);
    r.y = (unsigned)c | ((unsigned)d << 16);
    *(uint2*)(Vt + ((size_t)bh * HDsz + e0 + e_l) * Ssz + s0 + s4) = r;
  }
}

// ---------------------------------------------------------------------------
// Flash attention, bf16 MFMA, uniform split-K (<=16 k-tiles per block).
// nchunks(qt) = ceil((2qt+2)/16): qt 0..7 ->1, 8..15 ->2, 16..23 ->3,
// 24..31 ->4.  80 blocks per bh, heavy qt dispatched first.
// Chunk 0 writes (raw if n>1) O fp32 to At; chunks >=1 write bf16 partials
// to Pb (d_out scratch).  (m,l) per chunk -> mlb.  attn_merge recombines.
// P^T (C-layout) -> P (A-layout) via wave-private LDS round-trip (sP).
// ---------------------------------------------------------------------------
__global__ __launch_bounds__(256) void attn_mfma(const u16* __restrict__ Qg,
                                                 const u16* __restrict__ Kg,
                                                 const u16* __restrict__ Vtg,
                                                 float* __restrict__ At,
                                                 u16* __restrict__ Pb,
                                                 float* __restrict__ mlb) {
  const int x = blockIdx.x;  // 0..79, heavy first
  int qt, c, n;
  if (x < 32)      { qt = 31 - (x >> 2); c = x & 3; n = 4; }
  else if (x < 56) { int i = x - 32; qt = 23 - i / 3; c = i % 3; n = 3; }
  else if (x < 72) { int i = x - 56; qt = 15 - (i >> 1); c = i & 1; n = 2; }
  else             { qt = 79 - x; c = 0; n = 1; }
  const int bh = blockIdx.y, b = bh >> 2, h = bh & 3;
  const int tid = threadIdx.x, w = tid >> 6, lane = tid & 63;
  const int quad = lane >> 4, l15 = lane & 15;
  __shared__ u16 sK[32 * 260];
  __shared__ u16 sV[256 * 36];
  __shared__ u16 sP[4 * 16 * 36];  // per-wave P-transpose scratch
  u16* sPw = &sP[w * 576];
  const int q0w = qt * 64 + w * 16;
  bf16x8 qf[8];
  {
    const u16* qp = Qg + ((size_t)(b * Ssz) + q0w + l15) * Dsz + h * HDsz + quad * 8;
#pragma unroll
    for (int dd = 0; dd < 8; ++dd) qf[dd] = *(const bf16x8*)(qp + dd * 32);
  }
  f32x4 o[16] = {};
  float m_old = -1e30f, l = 0.f;
  const int total = 2 * qt + 2;
  const int kt_lo = c * total / n, kt_hi = (c + 1) * total / n;
  const int krow = tid >> 3, kseg = (tid & 7) * 32;
  const u16* kbase = Kg + ((size_t)(b * Ssz) + krow) * Dsz + h * HDsz + kseg;
  const u16* vbase = Vtg + ((size_t)bh * HDsz + tid) * Ssz;
  for (int kt = kt_lo; kt < kt_hi; ++kt) {
    const int j0 = kt * 32;
    __syncthreads();
    {
      const u16* kp = kbase + (size_t)j0 * Dsz;
      u16* dkp = &sK[krow * 260 + kseg];
#pragma unroll
      for (int i = 0; i < 4; ++i) *(uint4*)(dkp + i * 8) = *(const uint4*)(kp + i * 8);
      const u16* vp = vbase + j0;
      u16* dvp = &sV[tid * 36];
#pragma unroll
      for (int i = 0; i < 4; ++i) *(uint4*)(dvp + i * 8) = *(const uint4*)(vp + i * 8);
    }
    __syncthreads();
    // S^T = K*Q^T : A = K-frag (m=key), B = Q-frag (n=q)
    f32x4 s0v = {}, s1v = {};
#pragma unroll
    for (int dd = 0; dd < 8; ++dd) {
      bf16x8 a0 = *(const bf16x8*)&sK[l15 * 260 + dd * 32 + quad * 8];
      bf16x8 a1 = *(const bf16x8*)&sK[(16 + l15) * 260 + dd * 32 + quad * 8];
      s0v = __builtin_amdgcn_mfma_f32_16x16x32_bf16(a0, qf[dd], s0v, 0, 0, 0);
      s1v = __builtin_amdgcn_mfma_f32_16x16x32_bf16(a1, qf[dd], s1v, 0, 0, 0);
    }
    const int qg = q0w + l15;
    float p[8];
#pragma unroll
    for (int r = 0; r < 4; ++r) {
      const int kg = j0 + quad * 4 + r;
      p[r] = (kg <= qg) ? s0v[r] : -1e30f;
      p[4 + r] = (kg + 16 <= qg) ? s1v[r] : -1e30f;
    }
    // online softmax stats (per q = l15, across lanes {l, l^16, l^32, l^48})
    float mt = p[0];
#pragma unroll
    for (int i = 1; i < 8; ++i) mt = fmaxf(mt, p[i]);
    mt = fmaxf(mt, __shfl_xor(mt, 16));
    mt = fmaxf(mt, __shfl_xor(mt, 32));
    const float m_new = fmaxf(m_old, mt);
    const float alpha = __expf(m_old - m_new);
    float ts = 0.f;
#pragma unroll
    for (int i = 0; i < 8; ++i) { p[i] = __expf(p[i] - m_new); ts += p[i]; }
    ts += __shfl_xor(ts, 16);
    ts += __shfl_xor(ts, 32);
    l = l * alpha + ts;
    m_old = m_new;
    if (!__all(alpha == 1.0f)) {
      const float a0_ = __shfl(alpha, (lane & 48) | (quad * 4 + 0));
      const float a1_ = __shfl(alpha, (lane & 48) | (quad * 4 + 1));
      const float a2_ = __shfl(alpha, (lane & 48) | (quad * 4 + 2));
      const float a3_ = __shfl(alpha, (lane & 48) | (quad * 4 + 3));
#pragma unroll
      for (int ds = 0; ds < 16; ++ds) {
        o[ds][0] *= a0_; o[ds][1] *= a1_; o[ds][2] *= a2_; o[ds][3] *= a3_;
      }
    }
    // P^T (C-layout: key=quad*4+r[+16], q=l15) -> A-layout (m=q=l15,
    // k=key=quad*8+j) via wave-private LDS round-trip (no barrier).
    {
      uint2 lo, hi;
      lo.x = pk2(p[0], p[1]); lo.y = pk2(p[2], p[3]);
      hi.x = pk2(p[4], p[5]); hi.y = pk2(p[6], p[7]);
      *(uint2*)&sPw[l15 * 36 + quad * 4] = lo;
      *(uint2*)&sPw[l15 * 36 + 16 + quad * 4] = hi;
    }
    bf16x8 pf = *(const bf16x8*)&sPw[l15 * 36 + quad * 8];
    // PV: O[q][d] += P * V^T-frag (n=d=l15-major, k=key=quad*8+j)
#pragma unroll
    for (int ds = 0; ds < 16; ++ds) {
      bf16x8 bv = *(const bf16x8*)&sV[(ds * 16 + l15) * 36 + quad * 8];
      o[ds] = __builtin_amdgcn_mfma_f32_16x16x32_bf16(pf, bv, o[ds], 0, 0, 0);
    }
  }
  if (n == 1) {
    float lr[4];
#pragma unroll
    for (int r = 0; r < 4; ++r) lr[r] = 1.f / __shfl(l, (lane & 48) | (quad * 4 + r));
    float* ob = At + ((size_t)bh * Ssz + q0w + quad * 4) * HDsz + l15;
#pragma unroll
    for (int r = 0; r < 4; ++r)
#pragma unroll
      for (int ds = 0; ds < 16; ++ds)
        ob[(size_t)r * HDsz + ds * 16] = o[ds][r] * lr[r];
  } else {
    if (lane < 16) {
      const int idx = bh * 2048 + qt * 64 + w * 16 + l15;
      mlb[c * 32768 + idx] = m_old;
      mlb[131072 + c * 32768 + idx] = l;
    }
    if (c == 0) {
      float* ob = At + ((size_t)bh * Ssz + q0w + quad * 4) * HDsz + l15;
#pragma unroll
      for (int r = 0; r < 4; ++r)
#pragma unroll
        for (int ds = 0; ds < 16; ++ds)
          ob[(size_t)r * HDsz + ds * 16] = o[ds][r];
    } else {
      const int slotBase = (qt >= 24) ? 24 + (qt - 24) * 3
                         : (qt >= 16) ? 8 + (qt - 16) * 2 : (qt - 8);
      u16* dst = Pb + (size_t)(bh * 48 + slotBase + (c - 1)) * 16384 +
                 (size_t)(w * 16 + quad * 4) * HDsz + l15;
#pragma unroll
      for (int r = 0; r < 4; ++r)
#pragma unroll
        for (int ds = 0; ds < 16; ++ds)
          dst[(size_t)r * HDsz + ds * 16] = f2b(o[ds][r]);
    }
  }
}

// ---------------------------------------------------------------------------
// N-way merge of split-K chunks (qt >= 8): O = sum_c O_c e^{m_c-m*} /
// sum_c l_c e^{m_c-m*}.  grid (24, 16).
// ---------------------------------------------------------------------------
__global__ __launch_bounds__(256) void attn_merge(float* __restrict__ At,
                                                  const u16* __restrict__ Pb,
                                                  const float* __restrict__ mlb) {
  const int qt = 8 + blockIdx.x, bh = blockIdx.y;
  const int t = threadIdx.x;
  const int n = (qt >= 24) ? 4 : (qt >= 16) ? 3 : 2;
  const int slotBase = (qt >= 24) ? 24 + (qt - 24) * 3
                     : (qt >= 16) ? 8 + (qt - 16) * 2 : (qt - 8);
  float4* abase = (float4*)(At + ((size_t)bh * Ssz + qt * 64) * HDsz);
  const int mlbase = bh * 2048 + qt * 64;
#pragma unroll 4
  for (int i = 0; i < 16; ++i) {
    const int f = i * 256 + t;  // float4 index, 0..4095
    const int qr = f >> 6;
    float mc[4], lc[4];
    float mm = -1e30f;
#pragma unroll
    for (int cth = 0; cth < 4; ++cth)
      if (cth < n) {
        mc[cth] = mlb[cth * 32768 + mlbase + qr];
        lc[cth] = mlb[131072 + cth * 32768 + mlbase + qr];
        mm = fmaxf(mm, mc[cth]);
      }
    float wts[4], den = 0.f;
#pragma unroll
    for (int cth = 0; cth < 4; ++cth)
      if (cth < n) { wts[cth] = __expf(mc[cth] - mm); den += lc[cth] * wts[cth]; }
    const float inv = 1.f / den;
    float4 a = abase[f];
    float ox = a.x * wts[0], oy = a.y * wts[0], oz = a.z * wts[0], ow = a.w * wts[0];
#pragma unroll
    for (int cth = 1; cth < 4; ++cth)
      if (cth < n) {
        uint2 pv = *(const uint2*)(Pb + (size_t)(bh * 48 + slotBase + cth - 1) * 16384 +
                                   (size_t)f * 4);
        ox += wts[cth] * b2f(pv.x & 0xFFFFu);
        oy += wts[cth] * b2f(pv.x >> 16);
        oz += wts[cth] * b2f(pv.y & 0xFFFFu);
        ow += wts[cth] * b2f(pv.y >> 16);
      }
    float4 ov; ov.x = ox * inv; ov.y = oy * inv; ov.z = oz * inv; ov.w = ow * inv;
    abase[f] = ov;
  }
}

// ---------------------------------------------------------------------------
// Fused: sq=elu(q)+1, sk=elu(k)+1 (in place) + denq = sq.z, denk = sk.z.
// ---------------------------------------------------------------------------
__global__ __launch_bounds__(256) void eludens(float* __restrict__ Qb,
                                               float* __restrict__ Kb,
                                               const float* __restrict__ z,
                                               float* __restrict__ dq,
                                               float* __restrict__ dk) {
  const int wid = threadIdx.x >> 6, lane = threadIdx.x & 63;
  const int r = blockIdx.x * 4 + wid;
  const int b = r >> 13, h = (r >> 11) & 3, s = r & 2047;
  const size_t base = ((size_t)(b * Ssz + s)) * Dsz + h * HDsz + lane * 4;
  float4 z4 = *(const float4*)(z + h * HDsz + lane * 4);
  float4 q = *(float4*)(Qb + base);
  q.x = q.x > 0.f ? q.x + 1.f : __expf(q.x);
  q.y = q.y > 0.f ? q.y + 1.f : __expf(q.y);
  q.z = q.z > 0.f ? q.z + 1.f : __expf(q.z);
  q.w = q.w > 0.f ? q.w + 1.f : __expf(q.w);
  *(float4*)(Qb + base) = q;
  float4 k = *(float4*)(Kb + base);
  k.x = k.x > 0.f ? k.x + 1.f : __expf(k.x);
  k.y = k.y > 0.f ? k.y + 1.f : __expf(k.y);
  k.z = k.z > 0.f ? k.z + 1.f : __expf(k.z);
  k.w = k.w > 0.f ? k.w + 1.f : __expf(k.w);
  *(float4*)(Kb + base) = k;
  float pq = q.x * z4.x + q.y * z4.y + q.z * z4.z + q.w * z4.w;
  float pk = k.x * z4.x + k.y * z4.y + k.z * z4.z + k.w * z4.w;
#pragma unroll
  for (int off = 32; off; off >>= 1) {
    pq += __shfl_down(pq, off);
    pk += __shfl_down(pk, off);
  }
  if (lane == 0) { dq[r] = pq; dk[r] = pk; }
}

// ---------------------------------------------------------------------------
// Per-head MFMA GEMM: acc[m,e] = sum_d Asrc[m,h*256+d] * mem[h][d][e].
// mode 0: blend = g*acc/den + (1-g)*At -> bf16 row-major (bfout)
// mode 1: Vio = v - acc/den (fp32 in place)
// ---------------------------------------------------------------------------
__global__ __launch_bounds__(256) void memread_mfma(const float* __restrict__ Asrc,
                                                    const float* __restrict__ mem,
                                                    const float* __restrict__ dens,
                                                    const float* __restrict__ betas,
                                                    const float* __restrict__ At,
                                                    float* __restrict__ Vio,
                                                    u16* __restrict__ bfout, int mode) {
  const int h = blockIdx.z;
  const int tid = threadIdx.x, lane = tid & 63, w = tid >> 6;
  const int quad = lane >> 4, l15 = lane & 15;
  const int mw = (w >> 1) * 64, ew = (w & 1) * 64;
  const int m0 = blockIdx.y * 128, e0t = blockIdx.x * 128;
  __shared__ u16 sA[128 * 40];  // [m][k]
  __shared__ u16 sB[128 * 40];  // [e][k]
  const int srow = tid >> 1, sseg = (tid & 1) * 16;
  const int k4 = (tid & 7) * 4, e4 = (tid >> 3) * 4;
  f32x4 acc[4][4] = {};
  for (int k0 = 0; k0 < HDsz; k0 += 32) {
    __syncthreads();
    {
      const float* ap = Asrc + (size_t)(m0 + srow) * Dsz + h * HDsz + k0 + sseg;
      float4 f0 = *(const float4*)ap, f1 = *(const float4*)(ap + 4);
      float4 f2 = *(const float4*)(ap + 8), f3 = *(const float4*)(ap + 12);
      uint4 u0, u1;
      u0.x = pk2(f0.x, f0.y); u0.y = pk2(f0.z, f0.w);
      u0.z = pk2(f1.x, f1.y); u0.w = pk2(f1.z, f1.w);
      u1.x = pk2(f2.x, f2.y); u1.y = pk2(f2.z, f2.w);
      u1.z = pk2(f3.x, f3.y); u1.w = pk2(f3.z, f3.w);
      u16* dst = &sA[srow * 40 + sseg];
      *(uint4*)dst = u0; *(uint4*)(dst + 8) = u1;
    }
    {
      const float* bp = mem + (size_t)h * 65536 + (size_t)(k0 + k4) * HDsz + e0t + e4;
      float4 r0 = *(const float4*)bp;
      float4 r1 = *(const float4*)(bp + HDsz);
      float4 r2 = *(const float4*)(bp + 2 * HDsz);
      float4 r3 = *(const float4*)(bp + 3 * HDsz);
      const float* rr[4] = {(const float*)&r0, (const float*)&r1,
                            (const float*)&r2, (const float*)&r3};
#pragma unroll
      for (int cc = 0; cc < 4; ++cc) {
        uint2 u;
        u.x = pk2(rr[0][cc], rr[1][cc]);
        u.y = pk2(rr[2][cc], rr[3][cc]);
        *(uint2*)&sB[(e4 + cc) * 40 + k4] = u;
      }
    }
    __syncthreads();
    bf16x8 af[4], bfr[4];
#pragma unroll
    for (int i = 0; i < 4; ++i) {
      af[i] = *(const bf16x8*)&sA[(mw + i * 16 + l15) * 40 + quad * 8];
      bfr[i] = *(const bf16x8*)&sB[(ew + i * 16 + l15) * 40 + quad * 8];
    }
#pragma unroll
    for (int i = 0; i < 4; ++i)
#pragma unroll
      for (int j = 0; j < 4; ++j)
        acc[i][j] = __builtin_amdgcn_mfma_f32_16x16x32_bf16(af[i], bfr[j], acc[i][j], 0, 0, 0);
  }
  const float g = 1.f / (1.f + __expf(-betas[h]));
#pragma unroll
  for (int i = 0; i < 4; ++i) {
#pragma unroll
    for (int r = 0; r < 4; ++r) {
      const int m = m0 + mw + i * 16 + quad * 4 + r;
      const int b = m >> 11, s = m & 2047;
      const int rowidx = ((b << 2) + h) * Ssz + s;
      const float inv = 1.f / (dens[rowidx] + 1e-6f);
#pragma unroll
      for (int j = 0; j < 4; ++j) {
        const int e = e0t + ew + j * 16 + l15;
        const float av = acc[i][j][r] * inv;
        if (mode == 0) {
          const float a = At[(size_t)rowidx * HDsz + e];
          bfout[(size_t)m * Dsz + h * HDsz + e] = f2b(g * av + (1.f - g) * a);
        } else {
          float* p = Vio + (size_t)m * Dsz + h * HDsz + e;
          *p = *p - av;
        }
      }
    }
  }
}

// ---------------------------------------------------------------------------
// mem partials: P[(h*16+chunk)][d][e] = sum_{m in chunk} sk[m,..d]*W[m,..e]
// ---------------------------------------------------------------------------
__global__ __launch_bounds__(256) void mem_update_mfma(const float* __restrict__ SK,
                                                       const float* __restrict__ W,
                                                       float* __restrict__ P) {
  const int de = blockIdx.x;
  const int d0 = (de >> 1) * 128, e0 = (de & 1) * 128;
  const int h = blockIdx.y, chunk = blockIdx.z;
  const int m0 = chunk * 512;
  const int tid = threadIdx.x, lane = tid & 63, w = tid >> 6;
  const int quad = lane >> 4, l15 = lane & 15;
  const int dw = (w >> 1) * 64, ew = (w & 1) * 64;
  __shared__ u16 sA[128 * 40];  // [d][m]
  __shared__ u16 sB[128 * 40];  // [e][m]
  const int m4 = (tid & 7) * 4;
  const int c4 = (tid >> 3) * 4;
  f32x4 acc[4][4] = {};
  for (int mt = 0; mt < 512; mt += 32) {
    __syncthreads();
    const float* ka = SK + (size_t)(m0 + mt + m4) * Dsz + h * HDsz + d0 + c4;
    const float* wa = W + (size_t)(m0 + mt + m4) * Dsz + h * HDsz + e0 + c4;
    float4 a0 = *(const float4*)ka;
    float4 a1 = *(const float4*)(ka + Dsz);
    float4 a2 = *(const float4*)(ka + 2 * Dsz);
    float4 a3 = *(const float4*)(ka + 3 * Dsz);
    float4 b0 = *(const float4*)wa;
    float4 b1 = *(const float4*)(wa + Dsz);
    float4 b2 = *(const float4*)(wa + 2 * Dsz);
    float4 b3 = *(const float4*)(wa + 3 * Dsz);
    const float* aa[4] = {(const float*)&a0, (const float*)&a1,
                          (const float*)&a2, (const float*)&a3};
    const float* bb[4] = {(const float*)&b0, (const float*)&b1,
                          (const float*)&b2, (const float*)&b3};
#pragma unroll
    for (int cc = 0; cc < 4; ++cc) {
      uint2 ua, ub2;
      ua.x = pk2(aa[0][cc], aa[1][cc]); ua.y = pk2(aa[2][cc], aa[3][cc]);
      ub2.x = pk2(bb[0][cc], bb[1][cc]); ub2.y = pk2(bb[2][cc], bb[3][cc]);
      *(uint2*)&sA[(c4 + cc) * 40 + m4] = ua;
      *(uint2*)&sB[(c4 + cc) * 40 + m4] = ub2;
    }
    __syncthreads();
    bf16x8 af[4], bfr[4];
#pragma unroll
    for (int i = 0; i < 4; ++i) {
      af[i] = *(const bf16x8*)&sA[(dw + i * 16 + l15) * 40 + quad * 8];
      bfr[i] = *(const bf16x8*)&sB[(ew + i * 16 + l15) * 40 + quad * 8];
    }
#pragma unroll
    for (int i = 0; i < 4; ++i)
#pragma unroll
      for (int j = 0; j < 4; ++j)
        acc[i][j] = __builtin_amdgcn_mfma_f32_16x16x32_bf16(af[i], bfr[j], acc[i][j], 0, 0, 0);
  }
  float* Pp = P + ((size_t)(h * 16 + chunk)) * 65536;
#pragma unroll
  for (int i = 0; i < 4; ++i)
#pragma unroll
    for (int r = 0; r < 4; ++r) {
      const int d = d0 + dw + i * 16 + quad * 4 + r;
#pragma unroll
      for (int j = 0; j < 4; ++j) {
        const int e = e0 + ew + j * 16 + l15;
        Pp[(size_t)d * HDsz + e] = acc[i][j][r];
      }
    }
}

// ---------------------------------------------------------------------------
// outmem = mem + 0.25 * sum_{chunk} P[h*16+chunk]
// ---------------------------------------------------------------------------
__global__ __launch_bounds__(256) void mem_reduce(const float4* __restrict__ P,
                                                  const float4* __restrict__ mem,
                                                  float4* __restrict__ outmem) {
  const int gid = blockIdx.x * 256 + threadIdx.x;
  const int h = gid >> 14, off = gid & 16383;
  float sx = 0.f, sy = 0.f, sz = 0.f, sw = 0.f;
#pragma unroll 4
  for (int c = 0; c < 16; ++c) {
    float4 v = P[((size_t)(h * 16 + c) << 14) + off];
    sx += v.x; sy += v.y; sz += v.z; sw += v.w;
  }
  float4 m = mem[gid];
  float4 o;
  o.x = m.x + 0.25f * sx; o.y = m.y + 0.25f * sy;
  o.z = m.z + 0.25f * sz; o.w = m.w + 0.25f * sw;
  outmem[gid] = o;
}

// ---------------------------------------------------------------------------
// z_new[h][d] = z[h][d] + (1/B) sum_{b,s} sk[b,h,s,d]   grid 256 (h*64+chunk)
// ---------------------------------------------------------------------------
__global__ __launch_bounds__(256) void z_update(const float* __restrict__ SK,
                                                const float* __restrict__ z_in,
                                                float* __restrict__ z_out) {
  const int h = blockIdx.x >> 6, chunk = blockIdx.x & 63;
  const int t = threadIdx.x;
  const int m0 = chunk * 128;
  float sum = 0.f;
  for (int i = 0; i < 128; ++i) sum += SK[(size_t)(m0 + i) * Dsz + h * HDsz + t];
  float val = sum * 0.25f;
  if (chunk == 0) val += z_in[h * HDsz + t];
  atomicAdd(z_out + h * HDsz + t, val);
}

// ---------------------------------------------------------------------------
extern "C" void kernel_launch(void* const* d_in, const int* in_sizes, int n_in,
                              void* d_out, int out_size, void* d_ws, size_t ws_size,
                              hipStream_t stream) {
  (void)in_sizes; (void)n_in; (void)out_size; (void)ws_size;
  const float* Hs = (const float*)d_in[0];
  const float* Wq = (const float*)d_in[1];
  const float* Wk = (const float*)d_in[2];
  const float* Wv = (const float*)d_in[3];
  const float* Wo = (const float*)d_in[4];
  const float* bo = (const float*)d_in[5];
  const float* betas = (const float*)d_in[6];
  const float* mem = (const float*)d_in[7];
  const float* z = (const float*)d_in[8];

  // fp32 workspace region
  float* ws = (float*)d_ws;
  float* Qb = ws;                    // 8388608 : Q fp32 -> sq
  float* Kb = ws + 8388608;          // K fp32 -> sk
  float* Vb = ws + 16777216;         // V fp32 -> W = v - delta
  float* At = ws + 25165824;         // attn out fp32 [bh][s][e]
  float* dq = ws + 33554432;         // 32768
  float* dk = ws + 33587200;         // 32768
  float* mlb = ws + 33619968;        // 262144: m [4][16][2048], l at +131072
  // bf16 region
  u16* ub = (u16*)(ws + 33882112);
  u16* Wqb = ub;                     // 4 x 1048576 weight copies
  u16* Wkb = ub + 1048576;
  u16* Wvb = ub + 2097152;
  u16* Wob = ub + 3145728;
  u16* Qbf = ub + 4194304;           // bf16 Q; later reused as bf16 blend
  u16* Kbf = ub + 12582912;
  u16* Vt = ub + 20971520;           // 8388608 u16: Hs bf16 first, then V^T
  u16* Hsb = Vt;                     // alias: dead once V gemm done
  float* P = (float*)Vt;             // mem partials alias (dead after attn)
  u16* Vbf = (u16*)d_out;            // bf16 V row-major (d_out scratch)
  u16* Pb = (u16*)d_out;             // split-attn bf16 partials (25.2 MB),
                                     // live only between attn and merge

  float* out = (float*)d_out;                 // 8192x1024
  float* outmem = out + (size_t)Msz * Dsz;    // 4x256x256
  float* outz = outmem + Hsz * HDsz * HDsz;   // 4x256

  hipMemsetAsync(outz, 0, (size_t)(Hsz * HDsz) * sizeof(float), stream);

  cvt_bf16<<<1024, 256, 0, stream>>>((const float4*)Wq, Wqb);
  cvt_bf16<<<1024, 256, 0, stream>>>((const float4*)Wk, Wkb);
  cvt_bf16<<<1024, 256, 0, stream>>>((const float4*)Wv, Wvb);
  cvt_bf16<<<1024, 256, 0, stream>>>((const float4*)Wo, Wob);
  cvt_bf16<<<8192, 256, 0, stream>>>((const float4*)Hs, Hsb);

  dim3 gg(8, 64);  // N/128, M/128
  gemm_lds<<<gg, 256, 0, stream>>>(Hsb, Wqb, nullptr, Qb, Qbf);
  gemm_lds<<<gg, 256, 0, stream>>>(Hsb, Wkb, nullptr, Kb, Kbf);
  gemm_lds<<<gg, 256, 0, stream>>>(Hsb, Wvb, nullptr, Vb, Vbf);

  transpose_v<<<dim3(64, 8, 16), 256, 0, stream>>>(Vbf, Vt);
  attn_mfma<<<dim3(80, 16), 256, 0, stream>>>(Qbf, Kbf, Vt, At, Pb, mlb);
  attn_merge<<<dim3(24, 16), 256, 0, stream>>>(At, Pb, mlb);

  eludens<<<8192, 256, 0, stream>>>(Qb, Kb, z, dq, dk);

  memread_mfma<<<dim3(2, 64, 4), 256, 0, stream>>>(Qb, mem, dq, betas, At, nullptr, Qbf, 0);
  memread_mfma<<<dim3(2, 64, 4), 256, 0, stream>>>(Kb, mem, dk, betas, nullptr, Vb, nullptr, 1);

  mem_update_mfma<<<dim3(4, 4, 16), 256, 0, stream>>>(Kb, Vb, P);
  mem_reduce<<<256, 256, 0, stream>>>((const float4*)P, (const float4*)mem, (float4*)outmem);
  z_update<<<256, 256, 0, stream>>>(Kb, z, outz);

  gemm_lds<<<gg, 256, 0, stream>>>(Qbf, Wob, bo, out, nullptr);
}